// Round 6
// baseline (524.784 us; speedup 1.0000x reference)
//
#include <hip/hip_runtime.h>
#include <hip/hip_bf16.h>
#include <stdint.h>

// Problem constants
#define T_DIM 2048
#define B_DIM 8
#define D_DIM 1024
#define NSTATE 1024
#define BLKSZ 8
#define NB 128
#define M_DIM (T_DIM * B_DIM)   // 16384
#define N_DIM (3 * NSTATE)      // 3072 (k | v | q concatenated)
#define K_DIM D_DIM             // 1024

typedef __bf16 bf16x8 __attribute__((ext_vector_type(8)));
typedef float f32x4 __attribute__((ext_vector_type(4)));
typedef unsigned int uintx4 __attribute__((ext_vector_type(4)));

typedef __attribute__((address_space(3))) void lds_void;
typedef __attribute__((address_space(1))) const void glb_void;

__device__ __forceinline__ unsigned short f2bf(float f) {
  unsigned u = __float_as_uint(f);
  u = (u + 0x7FFFu + ((u >> 16) & 1u)) >> 16;  // RNE
  return (unsigned short)u;
}
// unpack bf16 #hi (0=low,1=high) from a packed u32, as float (1 VALU op)
__device__ __forceinline__ float bfu(unsigned r, int hi) {
  return __uint_as_float(hi ? (r & 0xFFFF0000u) : (r << 16));
}

__device__ __forceinline__ void load_lds16(const unsigned short* g,
                                           unsigned short* l) {
  __builtin_amdgcn_global_load_lds((glb_void*)g, (lds_void*)l, 16, 0, 0);
}

// DPP butterfly add (groups = physical lanes 8k..8k+7); compiler folds the
// update_dpp(0,...) + add into a single v_add_f32 dpp instruction.
template <int CTRL>
__device__ __forceinline__ float dpp_add(float x) {
  int y = __builtin_amdgcn_update_dpp(0, __float_as_int(x), CTRL, 0xF, 0xF, true);
  return x + __int_as_float(y);
}
// bare DPP move (value from the mirrored lane)
template <int CTRL>
__device__ __forceinline__ float dpp_mov(float x) {
  int y = __builtin_amdgcn_update_dpp(0, __float_as_int(x), CTRL, 0xF, 0xF, true);
  return __int_as_float(y);
}
__device__ __forceinline__ float reduce8(float x) {
  x = dpp_add<0xB1>(x);   // quad_perm(1,0,3,2): lane ^ 1
  x = dpp_add<0x4E>(x);   // quad_perm(2,3,0,1): lane ^ 2
  x = dpp_add<0x141>(x);  // row_half_mirror: crosses quads within 8-group
  return x;
}

// ---------------- Kernel 1: fp32 -> bf16 conversion of x and Wcat ----------
__global__ __launch_bounds__(256) void convert_kernel(
    const float* __restrict__ x, const float* __restrict__ Wk,
    const float* __restrict__ Wv, const float* __restrict__ Wq,
    unsigned short* __restrict__ xb, unsigned short* __restrict__ wb) {
  size_t idx = (size_t)blockIdx.x * blockDim.x + threadIdx.x;
  size_t row = idx >> 8;
  int c4 = (int)(idx & 255) * 4;
  const float* src;
  unsigned short* dst;
  if (row < (size_t)M_DIM) {
    src = x + row * K_DIM;
    dst = xb + row * K_DIM;
  } else {
    size_t r = row - M_DIM;
    const float* w = (r < 1024) ? Wk : (r < 2048 ? Wv : Wq);
    src = w + (r & 1023) * K_DIM;
    dst = wb + r * K_DIM;
  }
  float4 v = *(const float4*)(src + c4);
  ushort4 o;
  o.x = f2bf(v.x); o.y = f2bf(v.y); o.z = f2bf(v.z); o.w = f2bf(v.w);
  *(ushort4*)(dst + c4) = o;
}

// ---------------- Kernel 2: bf16 MFMA GEMM, 2-phase dbuf pipeline ----------
// R5 counters: MfmaUtil 21%, occupancy 1.7 blk/CU -> the 2-barrier m97
// structure exposed full global-load latency every K-step (barrier drains
// vmcnt(0) right after issuing the loads). Fix: double-buffered LDS, stage
// tile k+1 into buf^1 BEFORE computing tile k, ONE barrier per K-step ->
// load latency overlaps ds_read+MFMA. Unrolled x2 so buffer idx is static.
// Plus XCD-aware bijective swizzle (3072 % 8 == 0): each XCD owns 16
// contiguous mTiles -> A-tile fetched by one XCD's L2 only.
//
// pk layout per chain, per 8-step block (tblk = t/8), 192 ushorts:
//   seg*64 + elem*8 + (t%8)   with seg 0=k 1=v 2=q, elem = j (k,q) or i (v).
// k is normalized IN the epilogue (fp32, DPP reduce over 8 j-lanes).
#define BM 128
#define BN 128
#define BK 32
#define C_PLANE 49152  // ushorts per chain (256 tblk * 192)

__global__ __launch_bounds__(256) void gemm_kernel(
    const unsigned short* __restrict__ A,     // [M][K] bf16
    const unsigned short* __restrict__ Bmat,  // [N][K] bf16
    unsigned short* __restrict__ pk) {        // packed, layout above
  __shared__ unsigned short As[2][BM * BK];  // swizzled, unpadded, dbuf
  __shared__ unsigned short Bs[2][BN * BK];

  const int tid = threadIdx.x;
  const int nTiles = N_DIM / BN;  // 24
  const int nwg = (M_DIM / BM) * (N_DIM / BN);  // 3072, % 8 == 0
  const int bid = (int)blockIdx.x;
  const int swz = (bid & 7) * (nwg >> 3) + (bid >> 3);  // bijective XCD swizzle
  const int nTile = swz % nTiles;
  const int mTile = swz / nTiles;
  const int m0 = mTile * BM, n0 = nTile * BN;

  const int lane = tid & 63, wave = tid >> 6;
  const int wm = wave >> 1, wn = wave & 1;
  const int l15 = lane & 15, quad = lane >> 4;
  const int sw = quad ^ ((l15 >> 1) & 3);

  const int srow = lane >> 2;
  const int sblk = (lane & 3) ^ ((lane >> 3) & 3);
  const int c0 = wave, c1 = wave + 4;

  const unsigned short* gA0 = A + (size_t)(m0 + c0 * 16 + srow) * K_DIM + sblk * 8;
  const unsigned short* gA1 = A + (size_t)(m0 + c1 * 16 + srow) * K_DIM + sblk * 8;
  const unsigned short* gB0 = Bmat + (size_t)(n0 + c0 * 16 + srow) * K_DIM + sblk * 8;
  const unsigned short* gB1 = Bmat + (size_t)(n0 + c1 * 16 + srow) * K_DIM + sblk * 8;

  f32x4 acc[4][4];
#pragma unroll
  for (int mi = 0; mi < 4; mi++)
#pragma unroll
    for (int ni = 0; ni < 4; ni++) acc[mi][ni] = (f32x4){0.f, 0.f, 0.f, 0.f};

#define STAGE(KOFF, BUF)                         \
  {                                              \
    load_lds16(gA0 + (KOFF), As[BUF] + c0 * 512);\
    load_lds16(gA1 + (KOFF), As[BUF] + c1 * 512);\
    load_lds16(gB0 + (KOFF), Bs[BUF] + c0 * 512);\
    load_lds16(gB1 + (KOFF), Bs[BUF] + c1 * 512);\
  }

#define COMPUTE(BUF)                                                         \
  {                                                                          \
    bf16x8 af[4], bfr[4];                                                    \
    _Pragma("unroll") for (int mi = 0; mi < 4; mi++) {                       \
      uintx4 r =                                                             \
          *(const uintx4*)(As[BUF] + (wm * 64 + mi * 16 + l15) * BK + sw * 8);\
      af[mi] = __builtin_bit_cast(bf16x8, r);                                \
    }                                                                        \
    _Pragma("unroll") for (int ni = 0; ni < 4; ni++) {                       \
      uintx4 r =                                                             \
          *(const uintx4*)(Bs[BUF] + (wn * 64 + ni * 16 + l15) * BK + sw * 8);\
      bfr[ni] = __builtin_bit_cast(bf16x8, r);                               \
    }                                                                        \
    _Pragma("unroll") for (int mi = 0; mi < 4; mi++)                         \
        _Pragma("unroll") for (int ni = 0; ni < 4; ni++)                     \
            acc[mi][ni] = __builtin_amdgcn_mfma_f32_16x16x32_bf16(           \
                af[mi], bfr[ni], acc[mi][ni], 0, 0, 0);                      \
  }

  // prologue: stage k=0 into buf 0
  STAGE(0, 0);
  __syncthreads();  // drains vmcnt(0): buf0 ready

  // 2-phase pipeline, unrolled x2 (static buffer index). K/BK = 32 steps.
  for (int k0 = 0; k0 < K_DIM; k0 += 2 * BK) {
    STAGE(k0 + BK, 1);           // k0+BK <= 992 < K_DIM always
    COMPUTE(0);
    __syncthreads();             // drains vmcnt(0): buf1 ready
    const int kn = (k0 + 2 * BK < K_DIM) ? k0 + 2 * BK : 0;  // wrap: harmless
    STAGE(kn, 0);
    COMPUTE(1);
    __syncthreads();             // drains vmcnt(0): buf0 ready
  }

#undef STAGE
#undef COMPUTE

  // Epilogue: scatter into chain-major records; normalize k-segment rows.
#pragma unroll
  for (int mi = 0; mi < 4; mi++) {
#pragma unroll
    for (int ni = 0; ni < 4; ni++) {
      const int col = n0 + wn * 64 + ni * 16 + l15;
      const int seg = col >> 10;        // 0=k 1=v 2=q (uniform per block)
      const int wcol = col & 1023;
      const int nbq = wcol >> 3, jq = wcol & 7;
#pragma unroll
      for (int r = 0; r < 4; r++) {
        const int rowg = m0 + wm * 64 + mi * 16 + quad * 4 + r;
        const int t = rowg >> 3, bq = rowg & 7;
        float val = acc[mi][ni][r];
        if (seg == 0) {  // wave-uniform branch
          float ss = reduce8(val * val);  // ||k||^2 over the 8 j-lanes
          float rs = __builtin_amdgcn_rcpf(__builtin_amdgcn_sqrtf(ss) + 1e-6f);
          val *= rs;
        }
        const size_t addr = (size_t)(bq * NB + nbq) * C_PLANE +
                            (size_t)(t >> 3) * 192 + seg * 64 + jq * 8 +
                            (t & 7);
        pk[addr] = f2bf(val);
      }
    }
  }
}

// ---------------- Kernel 3: scan, element-per-lane, pinned 3-buf pipeline --
// (FROZEN this round - unchanged from R5 so its counters surface next round.)
#define C_2LOG2E 2.8853900817779268f   // 2*log2(e)
#define C_LOG2E  1.4426950408889634f

__global__ __launch_bounds__(64, 1) void scan_kernel(
    const unsigned short* __restrict__ pk, float* __restrict__ out) {
  const int chain = blockIdx.x;        // b*128+nb
  const int b = chain >> 7, nb = chain & 127;
  const int lane = threadIdx.x;
  const int i = lane >> 3, j = lane & 7;

  const unsigned short* pc = pk + (size_t)chain * C_PLANE;
  const int koff = j * 8, voff = 64 + i * 8, qoff = 128 + j * 8;

  float S = 0.f, T = 0.f, zsel = 0.f;
  // per-lane output pointer: t = tb*8 + j, column b*1024+nb*8+i
  float* outp = out + (size_t)j * (B_DIM * NSTATE) + b * NSTATE + nb * BLKSZ + i;

#define RELOAD(RK, RV, RQ, TNEXT)                          \
  {                                                        \
    const unsigned short* rec = pc + (size_t)(TNEXT) * 192;\
    RK = *(const uintx4*)(rec + koff);                     \
    RV = *(const uintx4*)(rec + voff);                     \
    RQ = *(const uintx4*)(rec + qoff);                     \
  }

#define CONSUME(RK, RV, RQ)                                                 \
  {                                                                         \
    _Pragma("unroll") for (int u = 0; u < 8; u++) {                         \
      float kf = bfu(RK[u >> 1], u & 1);                                    \
      float vf = bfu(RV[u >> 1], u & 1);                                    \
      float qf = bfu(RQ[u >> 1], u & 1);                                    \
      float kC = kf * C_2LOG2E;            /* off critical path */          \
      float base = fmaf(kC, vf, T);        /* off critical path */          \
      float p = S * kf;                                                     \
      p = dpp_add<0xB1>(p);                /* + lane^1 */                   \
      p = dpp_add<0x4E>(p);                /* + lane^2 -> quad sum q4 */    \
      float q4m = dpp_mov<0x141>(p);       /* partner quad's q4 */          \
      float u1 = fmaf(-kC, p, base);       /* parallel with dpp_mov */      \
      float a = fmaf(-kC, q4m, u1);        /* = T + kC*(v - sum8) */        \
      float e = __builtin_amdgcn_exp2f(a);                                  \
      float r_ = __builtin_amdgcn_rcpf(e + 1.f);                            \
      S = fmaf(-2.f, r_, 1.f);                                              \
      T = fmaf(-2.f * C_2LOG2E, r_, C_2LOG2E);                              \
      float z = S * qf;                                                     \
      z = dpp_add<0xB1>(z);                                                 \
      z = dpp_add<0x4E>(z);                                                 \
      z = dpp_add<0x141>(z);                                                \
      zsel = (j == u) ? z : zsel;          /* keeper lane for step u */     \
    }                                                                       \
    /* per-tblk epilogue: one trans pair + one full-wave coalesced store */ \
    float sg = __builtin_amdgcn_rcpf(                                       \
        1.f + __builtin_amdgcn_exp2f(zsel * -C_LOG2E));                     \
    *outp = zsel * zsel * sg;                                               \
    outp += 8 * (B_DIM * NSTATE);                                           \
  }

  uintx4 bk0, bv0, bq0, bk1, bv1, bq1, bk2, bv2, bq2;
  RELOAD(bk0, bv0, bq0, 0);
  RELOAD(bk1, bv1, bq1, 1);
  RELOAD(bk2, bv2, bq2, 2);
  __builtin_amdgcn_sched_barrier(0);

  // 255 = 85*3 tblks in the pipelined loop; tblk 255 is the drain tail.
  for (int tb = 0; tb < 255; tb += 3) {
    CONSUME(bk0, bv0, bq0);
    RELOAD(bk0, bv0, bq0, tb + 3);
    __builtin_amdgcn_sched_barrier(0);
    CONSUME(bk1, bv1, bq1);
    RELOAD(bk1, bv1, bq1, (tb + 4 < 256) ? tb + 4 : 255);
    __builtin_amdgcn_sched_barrier(0);
    CONSUME(bk2, bv2, bq2);
    RELOAD(bk2, bv2, bq2, (tb + 5 < 256) ? tb + 5 : 255);
    __builtin_amdgcn_sched_barrier(0);
  }
  CONSUME(bk0, bv0, bq0);

#undef RELOAD
#undef CONSUME

  // S_final: [B][NB][8][8]; lane (i,j) -> element i*8+j, coalesced
  out[(size_t)T_DIM * B_DIM * NSTATE + (size_t)chain * 64 + lane] = S;
}

// ---------------- launch ---------------------------------------------------
extern "C" void kernel_launch(void* const* d_in, const int* in_sizes, int n_in,
                              void* d_out, int out_size, void* d_ws,
                              size_t ws_size, hipStream_t stream) {
  const float* x = (const float*)d_in[0];
  const float* Wk = (const float*)d_in[1];
  const float* Wv = (const float*)d_in[2];
  const float* Wq = (const float*)d_in[3];
  float* out = (float*)d_out;

  unsigned short* xb = (unsigned short*)d_ws;                  // 32 MiB
  unsigned short* wb = xb + (size_t)M_DIM * K_DIM;             // 6 MiB
  unsigned short* pk = wb + (size_t)N_DIM * K_DIM;             // 96 MiB packed

  convert_kernel<<<M_DIM + N_DIM, 256, 0, stream>>>(x, Wk, Wv, Wq, xb, wb);
  gemm_kernel<<<(M_DIM / BM) * (N_DIM / BN), 256, 0, stream>>>(xb, wb, pk);
  scan_kernel<<<B_DIM * NB, 64, 0, stream>>>(pk, out);
}

// Round 7
// 435.964 us; speedup vs baseline: 1.2037x; 1.2037x over previous
//
#include <hip/hip_runtime.h>
#include <hip/hip_bf16.h>
#include <stdint.h>

// Problem constants
#define T_DIM 2048
#define B_DIM 8
#define D_DIM 1024
#define NSTATE 1024
#define BLKSZ 8
#define NB 128
#define M_DIM (T_DIM * B_DIM)   // 16384
#define N_DIM (3 * NSTATE)      // 3072 (k | v | q concatenated)
#define K_DIM D_DIM             // 1024

typedef __bf16 bf16x8 __attribute__((ext_vector_type(8)));
typedef float f32x4 __attribute__((ext_vector_type(4)));
typedef unsigned int uintx4 __attribute__((ext_vector_type(4)));

typedef __attribute__((address_space(3))) void lds_void;
typedef __attribute__((address_space(1))) const void glb_void;

__device__ __forceinline__ unsigned short f2bf(float f) {
  unsigned u = __float_as_uint(f);
  u = (u + 0x7FFFu + ((u >> 16) & 1u)) >> 16;  // RNE
  return (unsigned short)u;
}
// unpack bf16 #hi (0=low,1=high) from a packed u32, as float (1 VALU op)
__device__ __forceinline__ float bfu(unsigned r, int hi) {
  return __uint_as_float(hi ? (r & 0xFFFF0000u) : (r << 16));
}

__device__ __forceinline__ void load_lds16(const unsigned short* g,
                                           unsigned short* l) {
  __builtin_amdgcn_global_load_lds((glb_void*)g, (lds_void*)l, 16, 0, 0);
}

// DPP butterfly add (groups = physical lanes 8k..8k+7)
template <int CTRL>
__device__ __forceinline__ float dpp_add(float x) {
  int y = __builtin_amdgcn_update_dpp(0, __float_as_int(x), CTRL, 0xF, 0xF, true);
  return x + __int_as_float(y);
}
// bare DPP move (value from the mirrored lane)
template <int CTRL>
__device__ __forceinline__ float dpp_mov(float x) {
  int y = __builtin_amdgcn_update_dpp(0, __float_as_int(x), CTRL, 0xF, 0xF, true);
  return __int_as_float(y);
}
__device__ __forceinline__ float reduce8(float x) {
  x = dpp_add<0xB1>(x);   // quad_perm(1,0,3,2): lane ^ 1
  x = dpp_add<0x4E>(x);   // quad_perm(2,3,0,1): lane ^ 2
  x = dpp_add<0x141>(x);  // row_half_mirror: crosses quads within 8-group
  return x;
}

// ---------------- Kernel 1: fp32 -> bf16 conversion of x and Wcat ----------
__global__ __launch_bounds__(256) void convert_kernel(
    const float* __restrict__ x, const float* __restrict__ Wk,
    const float* __restrict__ Wv, const float* __restrict__ Wq,
    unsigned short* __restrict__ xb, unsigned short* __restrict__ wb) {
  size_t idx = (size_t)blockIdx.x * blockDim.x + threadIdx.x;
  size_t row = idx >> 8;
  int c4 = (int)(idx & 255) * 4;
  const float* src;
  unsigned short* dst;
  if (row < (size_t)M_DIM) {
    src = x + row * K_DIM;
    dst = xb + row * K_DIM;
  } else {
    size_t r = row - M_DIM;
    const float* w = (r < 1024) ? Wk : (r < 2048 ? Wv : Wq);
    src = w + (r & 1023) * K_DIM;
    dst = wb + r * K_DIM;
  }
  float4 v = *(const float4*)(src + c4);
  ushort4 o;
  o.x = f2bf(v.x); o.y = f2bf(v.y); o.z = f2bf(v.z); o.w = f2bf(v.w);
  *(ushort4*)(dst + c4) = o;
}

// ---------------- Kernel 2: bf16 MFMA GEMM, LDS-staged coalesced epilogue --
// R6 diagnosis: dur == hbm_bytes/1.8TB/s; WRITE 256MB vs pk=96MB (2.7x RMW
// amplification from 2-byte scatter stores), FETCH inflated ~100MB by the
// RMW line fetches. Fix: stage the block's pk slab in LDS (reusing the dead
// K-loop dbuf, exactly 32KB) and drain with 128-B-contiguous dwordx4 stores.
//
// pk inner record permuted to [seg][elem][ut_store], ut_store = (t&1)*4 +
// ((t&7)>>1): for acc (mi,quad,r), t&7 = 2mi+(quad>>1) so ut_store =
// (quad>>1)*4 + mi -> the 4 mi-siblings are CONSECUTIVE ushorts -> one
// ds_write_b64 per (ni,r). Scan reads the permutation with a static index.
#define BM 128
#define BN 128
#define BK 32
#define C_PLANE 49152  // ushorts per chain (256 tblk * 192)

__global__ __launch_bounds__(256) void gemm_kernel(
    const unsigned short* __restrict__ A,     // [M][K] bf16
    const unsigned short* __restrict__ Bmat,  // [N][K] bf16
    unsigned short* __restrict__ pk) {        // packed, layout above
  // 32 KB: K-loop As[2]/Bs[2] dbuf, then reused as epilogue staging.
  __shared__ unsigned short smem[16384];

  const int tid = threadIdx.x;
  const int nTiles = N_DIM / BN;  // 24
  const int nTile = blockIdx.x % nTiles;
  const int mTile = blockIdx.x / nTiles;
  const int m0 = mTile * BM, n0 = nTile * BN;

  const int lane = tid & 63, wave = tid >> 6;
  const int wm = wave >> 1, wn = wave & 1;
  const int l15 = lane & 15, quad = lane >> 4;
  const int sw = quad ^ ((l15 >> 1) & 3);

  const int srow = lane >> 2;
  const int sblk = (lane & 3) ^ ((lane >> 3) & 3);
  const int c0 = wave, c1 = wave + 4;

  const unsigned short* gA0 = A + (size_t)(m0 + c0 * 16 + srow) * K_DIM + sblk * 8;
  const unsigned short* gA1 = A + (size_t)(m0 + c1 * 16 + srow) * K_DIM + sblk * 8;
  const unsigned short* gB0 = Bmat + (size_t)(n0 + c0 * 16 + srow) * K_DIM + sblk * 8;
  const unsigned short* gB1 = Bmat + (size_t)(n0 + c1 * 16 + srow) * K_DIM + sblk * 8;

  f32x4 acc[4][4];
#pragma unroll
  for (int mi = 0; mi < 4; mi++)
#pragma unroll
    for (int ni = 0; ni < 4; ni++) acc[mi][ni] = (f32x4){0.f, 0.f, 0.f, 0.f};

#define STAGE(KOFF, BUF)                                          \
  {                                                               \
    load_lds16(gA0 + (KOFF), smem + (BUF)*4096 + c0 * 512);       \
    load_lds16(gA1 + (KOFF), smem + (BUF)*4096 + c1 * 512);       \
    load_lds16(gB0 + (KOFF), smem + 8192 + (BUF)*4096 + c0 * 512);\
    load_lds16(gB1 + (KOFF), smem + 8192 + (BUF)*4096 + c1 * 512);\
  }

#define COMPUTE(BUF)                                                          \
  {                                                                           \
    bf16x8 af[4], bfr[4];                                                     \
    _Pragma("unroll") for (int mi = 0; mi < 4; mi++) {                        \
      uintx4 r = *(const uintx4*)(smem + (BUF)*4096 +                         \
                                  (wm * 64 + mi * 16 + l15) * BK + sw * 8);   \
      af[mi] = __builtin_bit_cast(bf16x8, r);                                 \
    }                                                                         \
    _Pragma("unroll") for (int ni = 0; ni < 4; ni++) {                        \
      uintx4 r = *(const uintx4*)(smem + 8192 + (BUF)*4096 +                  \
                                  (wn * 64 + ni * 16 + l15) * BK + sw * 8);   \
      bfr[ni] = __builtin_bit_cast(bf16x8, r);                                \
    }                                                                         \
    _Pragma("unroll") for (int mi = 0; mi < 4; mi++)                          \
        _Pragma("unroll") for (int ni = 0; ni < 4; ni++)                      \
            acc[mi][ni] = __builtin_amdgcn_mfma_f32_16x16x32_bf16(            \
                af[mi], bfr[ni], acc[mi][ni], 0, 0, 0);                       \
  }

  // prologue: stage k=0 into buf 0
  STAGE(0, 0);
  __syncthreads();  // drains vmcnt(0): buf0 ready

  // 2-phase pipeline, unrolled x2 (static buffer index). K/BK = 32 steps.
  for (int k0 = 0; k0 < K_DIM; k0 += 2 * BK) {
    STAGE(k0 + BK, 1);           // k0+BK <= 992 < K_DIM always
    COMPUTE(0);
    __syncthreads();             // drains vmcnt(0): buf1 ready
    if (k0 + 2 * BK < K_DIM) STAGE(k0 + 2 * BK, 0);
    COMPUTE(1);
    __syncthreads();             // drains vmcnt(0): buf0 ready (or epilogue)
  }

#undef STAGE
#undef COMPUTE

  // ---- Epilogue phase 1: pack acc -> smem in pk-record image -------------
  // LDS ushort idx = ((wm*8+bq)*16+nbl)*64 + jq*8 + pq*4 + mi
  const int seg = n0 >> 10;        // 0=k 1=v 2=q (uniform per block)
  const int pq = quad >> 1;
  const int jq8 = (l15 & 7) * 8;
#pragma unroll
  for (int ni = 0; ni < 4; ni++) {
    const int nbl = (wn * 64 + ni * 16 + l15) >> 3;
#pragma unroll
    for (int r = 0; r < 4; r++) {
      const int bq = (quad * 4 + r) & 7;
      float w0 = acc[0][ni][r], w1 = acc[1][ni][r];
      float w2 = acc[2][ni][r], w3 = acc[3][ni][r];
      if (seg == 0) {  // wave-uniform: normalize each k-row over its 8 j-lanes
        float s0 = reduce8(w0 * w0), s1 = reduce8(w1 * w1);
        float s2 = reduce8(w2 * w2), s3 = reduce8(w3 * w3);
        w0 *= __builtin_amdgcn_rcpf(__builtin_amdgcn_sqrtf(s0) + 1e-6f);
        w1 *= __builtin_amdgcn_rcpf(__builtin_amdgcn_sqrtf(s1) + 1e-6f);
        w2 *= __builtin_amdgcn_rcpf(__builtin_amdgcn_sqrtf(s2) + 1e-6f);
        w3 *= __builtin_amdgcn_rcpf(__builtin_amdgcn_sqrtf(s3) + 1e-6f);
      }
      uint2 pr;
      pr.x = (unsigned)f2bf(w0) | ((unsigned)f2bf(w1) << 16);
      pr.y = (unsigned)f2bf(w2) | ((unsigned)f2bf(w3) << 16);
      const int idx = ((wm * 8 + bq) * 16 + nbl) * 64 + jq8 + pq * 4;
      *(uint2*)(smem + idx) = pr;  // 8-B aligned ds_write_b64
    }
  }
  __syncthreads();

  // ---- Epilogue phase 2: linear LDS read -> 128-B-coalesced pk stores ----
  const int tblk0 = m0 >> 6;          // mTile*2
  const int nbq0 = (n0 & 1023) >> 3;
#pragma unroll
  for (int it = 0; it < 8; it++) {
    const int chunk = it * 256 + tid;       // 0..2047, 16 B each
    const int jqc = chunk & 7;
    const int nblc = (chunk >> 3) & 15;
    const int bqc = (chunk >> 7) & 7;
    const int wmc = chunk >> 10;            // 0..1
    uintx4 d = *(const uintx4*)(smem + chunk * 8);
    const size_t addr = (size_t)(bqc * NB + nbq0 + nblc) * C_PLANE +
                        (size_t)(tblk0 + wmc) * 192 + seg * 64 + jqc * 8;
    *(uintx4*)(pk + addr) = d;
  }
}

// ---------------- Kernel 3: scan, element-per-lane, pinned 3-buf pipeline --
// Unchanged structure from R5; only the static ut_store permutation index s
// (pk inner layout changed to [seg][elem][ut_store], see gemm epilogue).
#define C_2LOG2E 2.8853900817779268f   // 2*log2(e)
#define C_LOG2E  1.4426950408889634f

__global__ __launch_bounds__(64, 1) void scan_kernel(
    const unsigned short* __restrict__ pk, float* __restrict__ out) {
  const int chain = blockIdx.x;        // b*128+nb
  const int b = chain >> 7, nb = chain & 127;
  const int lane = threadIdx.x;
  const int i = lane >> 3, j = lane & 7;

  const unsigned short* pc = pk + (size_t)chain * C_PLANE;
  const int koff = j * 8, voff = 64 + i * 8, qoff = 128 + j * 8;

  float S = 0.f, T = 0.f, zsel = 0.f;
  // per-lane output pointer: t = tb*8 + j, column b*1024+nb*8+i
  float* outp = out + (size_t)j * (B_DIM * NSTATE) + b * NSTATE + nb * BLKSZ + i;

#define RELOAD(RK, RV, RQ, TNEXT)                          \
  {                                                        \
    const unsigned short* rec = pc + (size_t)(TNEXT) * 192;\
    RK = *(const uintx4*)(rec + koff);                     \
    RV = *(const uintx4*)(rec + voff);                     \
    RQ = *(const uintx4*)(rec + qoff);                     \
  }

#define CONSUME(RK, RV, RQ)                                                 \
  {                                                                         \
    _Pragma("unroll") for (int u = 0; u < 8; u++) {                         \
      const int s = ((u & 1) << 2) | (u >> 1);  /* ut_store of step u */    \
      float kf = bfu(RK[s >> 1], s & 1);                                    \
      float vf = bfu(RV[s >> 1], s & 1);                                    \
      float qf = bfu(RQ[s >> 1], s & 1);                                    \
      float kC = kf * C_2LOG2E;            /* off critical path */          \
      float base = fmaf(kC, vf, T);        /* off critical path */          \
      float p = S * kf;                                                     \
      p = dpp_add<0xB1>(p);                /* + lane^1 */                   \
      p = dpp_add<0x4E>(p);                /* + lane^2 -> quad sum q4 */    \
      float q4m = dpp_mov<0x141>(p);       /* partner quad's q4 */          \
      float u1 = fmaf(-kC, p, base);       /* parallel with dpp_mov */      \
      float a = fmaf(-kC, q4m, u1);        /* = T + kC*(v - sum8) */        \
      float e = __builtin_amdgcn_exp2f(a);                                  \
      float r_ = __builtin_amdgcn_rcpf(e + 1.f);                            \
      S = fmaf(-2.f, r_, 1.f);                                              \
      T = fmaf(-2.f * C_2LOG2E, r_, C_2LOG2E);                              \
      float z = S * qf;                                                     \
      z = dpp_add<0xB1>(z);                                                 \
      z = dpp_add<0x4E>(z);                                                 \
      z = dpp_add<0x141>(z);                                                \
      zsel = (j == u) ? z : zsel;          /* keeper lane for step u */     \
    }                                                                       \
    /* per-tblk epilogue: one trans pair + one full-wave coalesced store */ \
    float sg = __builtin_amdgcn_rcpf(                                       \
        1.f + __builtin_amdgcn_exp2f(zsel * -C_LOG2E));                     \
    *outp = zsel * zsel * sg;                                               \
    outp += 8 * (B_DIM * NSTATE);                                           \
  }

  uintx4 bk0, bv0, bq0, bk1, bv1, bq1, bk2, bv2, bq2;
  RELOAD(bk0, bv0, bq0, 0);
  RELOAD(bk1, bv1, bq1, 1);
  RELOAD(bk2, bv2, bq2, 2);
  __builtin_amdgcn_sched_barrier(0);

  // 255 = 85*3 tblks in the pipelined loop; tblk 255 is the drain tail.
  for (int tb = 0; tb < 255; tb += 3) {
    CONSUME(bk0, bv0, bq0);
    RELOAD(bk0, bv0, bq0, tb + 3);
    __builtin_amdgcn_sched_barrier(0);
    CONSUME(bk1, bv1, bq1);
    RELOAD(bk1, bv1, bq1, (tb + 4 < 256) ? tb + 4 : 255);
    __builtin_amdgcn_sched_barrier(0);
    CONSUME(bk2, bv2, bq2);
    RELOAD(bk2, bv2, bq2, (tb + 5 < 256) ? tb + 5 : 255);
    __builtin_amdgcn_sched_barrier(0);
  }
  CONSUME(bk0, bv0, bq0);

#undef RELOAD
#undef CONSUME

  // S_final: [B][NB][8][8]; lane (i,j) -> element i*8+j, coalesced
  out[(size_t)T_DIM * B_DIM * NSTATE + (size_t)chain * 64 + lane] = S;
}

// ---------------- launch ---------------------------------------------------
extern "C" void kernel_launch(void* const* d_in, const int* in_sizes, int n_in,
                              void* d_out, int out_size, void* d_ws,
                              size_t ws_size, hipStream_t stream) {
  const float* x = (const float*)d_in[0];
  const float* Wk = (const float*)d_in[1];
  const float* Wv = (const float*)d_in[2];
  const float* Wq = (const float*)d_in[3];
  float* out = (float*)d_out;

  unsigned short* xb = (unsigned short*)d_ws;                  // 32 MiB
  unsigned short* wb = xb + (size_t)M_DIM * K_DIM;             // 6 MiB
  unsigned short* pk = wb + (size_t)N_DIM * K_DIM;             // 96 MiB packed

  convert_kernel<<<M_DIM + N_DIM, 256, 0, stream>>>(x, Wk, Wv, Wq, xb, wb);
  gemm_kernel<<<(M_DIM / BM) * (N_DIM / BN), 256, 0, stream>>>(xb, wb, pk);
  scan_kernel<<<B_DIM * NB, 64, 0, stream>>>(pk, out);
}

// Round 8
// 431.106 us; speedup vs baseline: 1.2173x; 1.0113x over previous
//
#include <hip/hip_runtime.h>
#include <hip/hip_bf16.h>
#include <stdint.h>

// Problem constants
#define T_DIM 2048
#define B_DIM 8
#define D_DIM 1024
#define NSTATE 1024
#define BLKSZ 8
#define NB 128
#define M_DIM (T_DIM * B_DIM)   // 16384
#define N_DIM (3 * NSTATE)      // 3072 (k | v | q concatenated)
#define K_DIM D_DIM             // 1024

typedef __bf16 bf16x8 __attribute__((ext_vector_type(8)));
typedef float f32x4 __attribute__((ext_vector_type(4)));
typedef unsigned int uintx4 __attribute__((ext_vector_type(4)));

typedef __attribute__((address_space(3))) void lds_void;
typedef __attribute__((address_space(1))) const void glb_void;

__device__ __forceinline__ unsigned short f2bf(float f) {
  unsigned u = __float_as_uint(f);
  u = (u + 0x7FFFu + ((u >> 16) & 1u)) >> 16;  // RNE
  return (unsigned short)u;
}
// unpack bf16 #hi (0=low,1=high) from a packed u32, as float (1 VALU op)
__device__ __forceinline__ float bfu(unsigned r, int hi) {
  return __uint_as_float(hi ? (r & 0xFFFF0000u) : (r << 16));
}

__device__ __forceinline__ void load_lds16(const unsigned short* g,
                                           unsigned short* l) {
  __builtin_amdgcn_global_load_lds((glb_void*)g, (lds_void*)l, 16, 0, 0);
}

// DPP butterfly add (groups = physical lanes 8k..8k+7)
template <int CTRL>
__device__ __forceinline__ float dpp_add(float x) {
  int y = __builtin_amdgcn_update_dpp(0, __float_as_int(x), CTRL, 0xF, 0xF, true);
  return x + __int_as_float(y);
}
// bare DPP move (value from the mirrored lane)
template <int CTRL>
__device__ __forceinline__ float dpp_mov(float x) {
  int y = __builtin_amdgcn_update_dpp(0, __float_as_int(x), CTRL, 0xF, 0xF, true);
  return __int_as_float(y);
}
__device__ __forceinline__ float reduce8(float x) {
  x = dpp_add<0xB1>(x);   // quad_perm(1,0,3,2): lane ^ 1
  x = dpp_add<0x4E>(x);   // quad_perm(2,3,0,1): lane ^ 2
  x = dpp_add<0x141>(x);  // row_half_mirror: crosses quads within 8-group
  return x;
}

// ---------------- Kernel 1: fp32 -> bf16 conversion of x and Wcat ----------
__global__ __launch_bounds__(256) void convert_kernel(
    const float* __restrict__ x, const float* __restrict__ Wk,
    const float* __restrict__ Wv, const float* __restrict__ Wq,
    unsigned short* __restrict__ xb, unsigned short* __restrict__ wb) {
  size_t idx = (size_t)blockIdx.x * blockDim.x + threadIdx.x;
  size_t row = idx >> 8;
  int c4 = (int)(idx & 255) * 4;
  const float* src;
  unsigned short* dst;
  if (row < (size_t)M_DIM) {
    src = x + row * K_DIM;
    dst = xb + row * K_DIM;
  } else {
    size_t r = row - M_DIM;
    const float* w = (r < 1024) ? Wk : (r < 2048 ? Wv : Wq);
    src = w + (r & 1023) * K_DIM;
    dst = wb + r * K_DIM;
  }
  float4 v = *(const float4*)(src + c4);
  ushort4 o;
  o.x = f2bf(v.x); o.y = f2bf(v.y); o.z = f2bf(v.z); o.w = f2bf(v.w);
  *(ushort4*)(dst + c4) = o;
}

// ---------------- Kernel 2: bf16 MFMA GEMM, LDS-staged coalesced epilogue --
// (FROZEN from R7 - WRITE amplification fixed, gemm left the top-5.)
// pk inner record [seg][elem][ut_store], ut_store = (t&1)*4 + ((t&7)>>1).
#define BM 128
#define BN 128
#define BK 32
#define C_PLANE 49152  // ushorts per chain (256 tblk * 192)

__global__ __launch_bounds__(256) void gemm_kernel(
    const unsigned short* __restrict__ A,     // [M][K] bf16
    const unsigned short* __restrict__ Bmat,  // [N][K] bf16
    unsigned short* __restrict__ pk) {        // packed, layout above
  // 32 KB: K-loop As[2]/Bs[2] dbuf, then reused as epilogue staging.
  __shared__ unsigned short smem[16384];

  const int tid = threadIdx.x;
  const int nTiles = N_DIM / BN;  // 24
  const int nTile = blockIdx.x % nTiles;
  const int mTile = blockIdx.x / nTiles;
  const int m0 = mTile * BM, n0 = nTile * BN;

  const int lane = tid & 63, wave = tid >> 6;
  const int wm = wave >> 1, wn = wave & 1;
  const int l15 = lane & 15, quad = lane >> 4;
  const int sw = quad ^ ((l15 >> 1) & 3);

  const int srow = lane >> 2;
  const int sblk = (lane & 3) ^ ((lane >> 3) & 3);
  const int c0 = wave, c1 = wave + 4;

  const unsigned short* gA0 = A + (size_t)(m0 + c0 * 16 + srow) * K_DIM + sblk * 8;
  const unsigned short* gA1 = A + (size_t)(m0 + c1 * 16 + srow) * K_DIM + sblk * 8;
  const unsigned short* gB0 = Bmat + (size_t)(n0 + c0 * 16 + srow) * K_DIM + sblk * 8;
  const unsigned short* gB1 = Bmat + (size_t)(n0 + c1 * 16 + srow) * K_DIM + sblk * 8;

  f32x4 acc[4][4];
#pragma unroll
  for (int mi = 0; mi < 4; mi++)
#pragma unroll
    for (int ni = 0; ni < 4; ni++) acc[mi][ni] = (f32x4){0.f, 0.f, 0.f, 0.f};

#define STAGE(KOFF, BUF)                                          \
  {                                                               \
    load_lds16(gA0 + (KOFF), smem + (BUF)*4096 + c0 * 512);       \
    load_lds16(gA1 + (KOFF), smem + (BUF)*4096 + c1 * 512);       \
    load_lds16(gB0 + (KOFF), smem + 8192 + (BUF)*4096 + c0 * 512);\
    load_lds16(gB1 + (KOFF), smem + 8192 + (BUF)*4096 + c1 * 512);\
  }

#define COMPUTE(BUF)                                                          \
  {                                                                           \
    bf16x8 af[4], bfr[4];                                                     \
    _Pragma("unroll") for (int mi = 0; mi < 4; mi++) {                        \
      uintx4 r = *(const uintx4*)(smem + (BUF)*4096 +                         \
                                  (wm * 64 + mi * 16 + l15) * BK + sw * 8);   \
      af[mi] = __builtin_bit_cast(bf16x8, r);                                 \
    }                                                                         \
    _Pragma("unroll") for (int ni = 0; ni < 4; ni++) {                        \
      uintx4 r = *(const uintx4*)(smem + 8192 + (BUF)*4096 +                  \
                                  (wn * 64 + ni * 16 + l15) * BK + sw * 8);   \
      bfr[ni] = __builtin_bit_cast(bf16x8, r);                                \
    }                                                                         \
    _Pragma("unroll") for (int mi = 0; mi < 4; mi++)                          \
        _Pragma("unroll") for (int ni = 0; ni < 4; ni++)                      \
            acc[mi][ni] = __builtin_amdgcn_mfma_f32_16x16x32_bf16(            \
                af[mi], bfr[ni], acc[mi][ni], 0, 0, 0);                       \
  }

  // prologue: stage k=0 into buf 0
  STAGE(0, 0);
  __syncthreads();  // drains vmcnt(0): buf0 ready

  // 2-phase pipeline, unrolled x2 (static buffer index). K/BK = 32 steps.
  for (int k0 = 0; k0 < K_DIM; k0 += 2 * BK) {
    STAGE(k0 + BK, 1);           // k0+BK <= 992 < K_DIM always
    COMPUTE(0);
    __syncthreads();             // drains vmcnt(0): buf1 ready
    if (k0 + 2 * BK < K_DIM) STAGE(k0 + 2 * BK, 0);
    COMPUTE(1);
    __syncthreads();             // drains vmcnt(0): buf0 ready (or epilogue)
  }

#undef STAGE
#undef COMPUTE

  // ---- Epilogue phase 1: pack acc -> smem in pk-record image -------------
  // LDS ushort idx = ((wm*8+bq)*16+nbl)*64 + jq*8 + pq*4 + mi
  const int seg = n0 >> 10;        // 0=k 1=v 2=q (uniform per block)
  const int pq = quad >> 1;
  const int jq8 = (l15 & 7) * 8;
#pragma unroll
  for (int ni = 0; ni < 4; ni++) {
    const int nbl = (wn * 64 + ni * 16 + l15) >> 3;
#pragma unroll
    for (int r = 0; r < 4; r++) {
      const int bq = (quad * 4 + r) & 7;
      float w0 = acc[0][ni][r], w1 = acc[1][ni][r];
      float w2 = acc[2][ni][r], w3 = acc[3][ni][r];
      if (seg == 0) {  // wave-uniform: normalize each k-row over its 8 j-lanes
        float s0 = reduce8(w0 * w0), s1 = reduce8(w1 * w1);
        float s2 = reduce8(w2 * w2), s3 = reduce8(w3 * w3);
        w0 *= __builtin_amdgcn_rcpf(__builtin_amdgcn_sqrtf(s0) + 1e-6f);
        w1 *= __builtin_amdgcn_rcpf(__builtin_amdgcn_sqrtf(s1) + 1e-6f);
        w2 *= __builtin_amdgcn_rcpf(__builtin_amdgcn_sqrtf(s2) + 1e-6f);
        w3 *= __builtin_amdgcn_rcpf(__builtin_amdgcn_sqrtf(s3) + 1e-6f);
      }
      uint2 pr;
      pr.x = (unsigned)f2bf(w0) | ((unsigned)f2bf(w1) << 16);
      pr.y = (unsigned)f2bf(w2) | ((unsigned)f2bf(w3) << 16);
      const int idx = ((wm * 8 + bq) * 16 + nbl) * 64 + jq8 + pq * 4;
      *(uint2*)(smem + idx) = pr;  // 8-B aligned ds_write_b64
    }
  }
  __syncthreads();

  // ---- Epilogue phase 2: linear LDS read -> 128-B-coalesced pk stores ----
  const int tblk0 = m0 >> 6;          // mTile*2
  const int nbq0 = (n0 & 1023) >> 3;
#pragma unroll
  for (int it = 0; it < 8; it++) {
    const int chunk = it * 256 + tid;       // 0..2047, 16 B each
    const int jqc = chunk & 7;
    const int nblc = (chunk >> 3) & 15;
    const int bqc = (chunk >> 7) & 7;
    const int wmc = chunk >> 10;            // 0..1
    uintx4 d = *(const uintx4*)(smem + chunk * 8);
    const size_t addr = (size_t)(bqc * NB + nbq0 + nblc) * C_PLANE +
                        (size_t)(tblk0 + wmc) * 192 + seg * 64 + jqc * 8;
    *(uintx4*)(pk + addr) = d;
  }
}

// ---------------- Kernel 3: scan, producer/consumer wave pair --------------
// R7 counters: 239 cy/step wall, 105 issue, chain ~60 -> ~134 cy of exposed
// latency with exactly 1 wave/SIMD (zero hiding; chain count = SIMD count).
// Fix: 2 waves per chain. Wave A runs the serial S/T recurrence (k,v
// streams) and publishes S per tblk into a double-buffered 4KB LDS slab
// ([u][lane], conflict-free). Wave B lags one tblk: reads S, computes
// z = sum_j S*q, sigmoid, coalesced store (q stream). 2048 waves ->
// 2/SIMD: B's ~20 cy/step fills A's stall slots. Barriers 2/tblk, matched
// across both waves.
#define C_2LOG2E 2.8853900817779268f   // 2*log2(e)
#define C_LOG2E  1.4426950408889634f

__global__ __launch_bounds__(128, 1) void scan_kernel(
    const unsigned short* __restrict__ pk, float* __restrict__ out) {
  __shared__ float slab[1024];         // [parity][u][lane] = 2*8*64
  const int chain = blockIdx.x;        // b*128+nb
  const int b = chain >> 7, nb = chain & 127;
  const int lane = threadIdx.x & 63;
  const bool waveA = (threadIdx.x < 64);
  const int i = lane >> 3, j = lane & 7;

  const unsigned short* pc = pk + (size_t)chain * C_PLANE;

  if (waveA) {
    // ---------------- producer: serial recurrence ----------------
    const int koff = j * 8, voff = 64 + i * 8;
    float S = 0.f, T = 0.f;
    uintx4 ka, va, kb, vb;
#define RELOAD_A(RK, RV, TB)                                 \
    {                                                        \
      const unsigned short* rec = pc + (size_t)(TB) * 192;   \
      RK = *(const uintx4*)(rec + koff);                     \
      RV = *(const uintx4*)(rec + voff);                     \
    }
#define CONSUME_A(RK, RV, PAR)                                              \
    {                                                                       \
      _Pragma("unroll") for (int u = 0; u < 8; u++) {                       \
        const int s = ((u & 1) << 2) | (u >> 1);  /* ut_store of step u */  \
        float kf = bfu(RK[s >> 1], s & 1);                                  \
        float vf = bfu(RV[s >> 1], s & 1);                                  \
        float kC = kf * C_2LOG2E;            /* off critical path */        \
        float base = fmaf(kC, vf, T);        /* off critical path */        \
        float p = S * kf;                                                   \
        p = dpp_add<0xB1>(p);                /* + lane^1 */                 \
        p = dpp_add<0x4E>(p);                /* + lane^2 -> quad sum */     \
        float q4m = dpp_mov<0x141>(p);       /* partner quad's sum */       \
        float u1 = fmaf(-kC, p, base);       /* parallel with dpp_mov */    \
        float a = fmaf(-kC, q4m, u1);        /* = T + kC*(v - sum8) */      \
        float e = __builtin_amdgcn_exp2f(a);                                \
        float r_ = __builtin_amdgcn_rcpf(e + 1.f);                          \
        S = fmaf(-2.f, r_, 1.f);                                            \
        T = fmaf(-2.f * C_2LOG2E, r_, C_2LOG2E);                            \
        slab[(PAR) * 512 + u * 64 + lane] = S;                              \
      }                                                                     \
    }
    RELOAD_A(ka, va, 0);
    __builtin_amdgcn_sched_barrier(0);
    for (int ot = 0; ot < 128; ot++) {
      RELOAD_A(kb, vb, 2 * ot + 1);
      __builtin_amdgcn_sched_barrier(0);
      CONSUME_A(ka, va, 0);
      __syncthreads();
      if (ot < 127) RELOAD_A(ka, va, 2 * ot + 2);
      __builtin_amdgcn_sched_barrier(0);
      CONSUME_A(kb, vb, 1);
      __syncthreads();
    }
    // S_final: [B][NB][8][8]; lane (i,j) -> element i*8+j, coalesced
    out[(size_t)T_DIM * B_DIM * NSTATE + (size_t)chain * 64 + lane] = S;
#undef RELOAD_A
#undef CONSUME_A
  } else {
    // ---------------- consumer: output phase, lags one tblk ----------------
    const int qoff = 128 + j * 8;
    float* outB =
        out + (size_t)j * (B_DIM * NSTATE) + b * NSTATE + nb * BLKSZ + i;
    uintx4 q0, q1;
#define RELOAD_Q(RQ, TB) \
    { RQ = *(const uintx4*)(pc + (size_t)(TB) * 192 + qoff); }
#define CONSUME_B(RQ, PAR, TBLK)                                            \
    {                                                                       \
      float zsel = 0.f;                                                     \
      _Pragma("unroll") for (int u = 0; u < 8; u++) {                       \
        const int s = ((u & 1) << 2) | (u >> 1);                            \
        float qf = bfu(RQ[s >> 1], s & 1);                                  \
        float Su = slab[(PAR) * 512 + u * 64 + lane];                       \
        float z = Su * qf;                                                  \
        z = dpp_add<0xB1>(z);                                               \
        z = dpp_add<0x4E>(z);                                               \
        z = dpp_add<0x141>(z);                                              \
        zsel = (j == u) ? z : zsel;        /* keeper lane for step u */     \
      }                                                                     \
      float sg = __builtin_amdgcn_rcpf(                                     \
          1.f + __builtin_amdgcn_exp2f(zsel * -C_LOG2E));                   \
      outB[(size_t)(TBLK) * 8 * (B_DIM * NSTATE)] = zsel * zsel * sg;       \
    }
    RELOAD_Q(q0, 0);
    for (int ot = 0; ot < 128; ot++) {
      if (ot > 0) CONSUME_B(q1, 1, 2 * ot - 1);
      RELOAD_Q(q1, 2 * ot + 1);
      __syncthreads();
      CONSUME_B(q0, 0, 2 * ot);
      if (ot < 127) RELOAD_Q(q0, 2 * ot + 2);
      __syncthreads();
    }
    CONSUME_B(q1, 1, 255);   // tail: tblk 255 (slab written before last barrier)
#undef RELOAD_Q
#undef CONSUME_B
  }
}

// ---------------- launch ---------------------------------------------------
extern "C" void kernel_launch(void* const* d_in, const int* in_sizes, int n_in,
                              void* d_out, int out_size, void* d_ws,
                              size_t ws_size, hipStream_t stream) {
  const float* x = (const float*)d_in[0];
  const float* Wk = (const float*)d_in[1];
  const float* Wv = (const float*)d_in[2];
  const float* Wq = (const float*)d_in[3];
  float* out = (float*)d_out;

  unsigned short* xb = (unsigned short*)d_ws;                  // 32 MiB
  unsigned short* wb = xb + (size_t)M_DIM * K_DIM;             // 6 MiB
  unsigned short* pk = wb + (size_t)N_DIM * K_DIM;             // 96 MiB packed

  convert_kernel<<<M_DIM + N_DIM, 256, 0, stream>>>(x, Wk, Wv, Wq, xb, wb);
  gemm_kernel<<<(M_DIM / BM) * (N_DIM / BN), 256, 0, stream>>>(xb, wb, pk);
  scan_kernel<<<B_DIM * NB, 128, 0, stream>>>(pk, out);
}